// Round 1
// baseline (209.839 us; speedup 1.0000x reference)
//
#include <hip/hip_runtime.h>
#include <cstdint>
#include <cstddef>

typedef unsigned short u16;
typedef unsigned int u32;
typedef u16 u16x4 __attribute__((ext_vector_type(4)));
typedef u16 u16x8 __attribute__((ext_vector_type(8)));
typedef __bf16 bf16x8 __attribute__((ext_vector_type(8)));
typedef float f32x4 __attribute__((ext_vector_type(4)));

#define B_   2
#define N_   2048
#define F_   512
#define D_   512
#define W_   128
#define E3   1536   /* 3*D */
#define MTOT 4096   /* B*N */

/* ---------------- QKV GEMM: qkv[m][e] = sum_k x[m][k] * W[e][k] ----------------
 * bf16 hi/lo split (3 MFMA passes, lo*lo dropped) for fp32-grade accuracy on the
 * 2% absmax budget. 128x128 tile, BK=32, 4 waves of 64x64, 16x16x32 MFMA. */
#define TM 128
#define TE 128
#define BK 32
#define LDK 40  /* padded k-stride in u16 (80 B rows: 16B-aligned, conflict-light) */

__device__ __forceinline__ u16 bf_hi(float f) {
  u32 u = __float_as_uint(f);
  return (u16)((u + 0x7fffu + ((u >> 16) & 1u)) >> 16); /* RNE truncate to bf16 */
}
__device__ __forceinline__ float bf_f(u16 h) { return __uint_as_float(((u32)h) << 16); }

__device__ __forceinline__ void cvt4(const float4 v, u16x4& h, u16x4& l) {
  h.x = bf_hi(v.x); l.x = bf_hi(v.x - bf_f(h.x));
  h.y = bf_hi(v.y); l.y = bf_hi(v.y - bf_f(h.y));
  h.z = bf_hi(v.z); l.z = bf_hi(v.z - bf_f(h.z));
  h.w = bf_hi(v.w); l.w = bf_hi(v.w - bf_f(h.w));
}

__device__ __forceinline__ f32x4 mfma_bf16(u16x8 a, u16x8 b, f32x4 c) {
  return __builtin_amdgcn_mfma_f32_16x16x32_bf16(
      __builtin_bit_cast(bf16x8, a), __builtin_bit_cast(bf16x8, b), c, 0, 0, 0);
}

__global__ __launch_bounds__(256) void qkv_gemm(const float* __restrict__ X,
                                                const float* __restrict__ Wl,
                                                float* __restrict__ QKV) {
  __shared__ __align__(16) u16 AsH[TM * LDK];
  __shared__ __align__(16) u16 AsL[TM * LDK];
  __shared__ __align__(16) u16 BsH[TE * LDK];
  __shared__ __align__(16) u16 BsL[TE * LDK];

  const int tid = threadIdx.x;
  const int m0 = blockIdx.x * TM;
  const int e0 = blockIdx.y * TE;
  const int lane = tid & 63;
  const int wave = tid >> 6;
  const int wm = (wave >> 1) * 64;   /* wave's M offset in tile */
  const int we = (wave & 1) * 64;    /* wave's E offset in tile */
  const int qd = lane >> 4;          /* quad 0..3 */
  const int l16 = lane & 15;

  /* staging: thread -> (row = tid>>1, 16 consecutive k at (tid&1)*16) */
  const int srow = tid >> 1;
  const int skoff = (tid & 1) * 16;

  f32x4 acc[4][4];
#pragma unroll
  for (int i = 0; i < 4; ++i)
#pragma unroll
    for (int j = 0; j < 4; ++j) acc[i][j] = (f32x4){0.f, 0.f, 0.f, 0.f};

  const float* ag = X + (size_t)(m0 + srow) * F_ + skoff;
  const float* bg = Wl + (size_t)(e0 + srow) * F_ + skoff;
  u16* aHp = &AsH[srow * LDK + skoff];
  u16* aLp = &AsL[srow * LDK + skoff];
  u16* bHp = &BsH[srow * LDK + skoff];
  u16* bLp = &BsL[srow * LDK + skoff];

  for (int k0 = 0; k0 < F_; k0 += BK) {
#pragma unroll
    for (int i = 0; i < 4; ++i) {
      float4 av = *(const float4*)(ag + k0 + 4 * i);
      float4 bv = *(const float4*)(bg + k0 + 4 * i);
      u16x4 h, l;
      cvt4(av, h, l);
      *(u16x4*)(aHp + 4 * i) = h;
      *(u16x4*)(aLp + 4 * i) = l;
      cvt4(bv, h, l);
      *(u16x4*)(bHp + 4 * i) = h;
      *(u16x4*)(bLp + 4 * i) = l;
    }
    __syncthreads();

    u16x8 fAH[4], fAL[4], fBH[4], fBL[4];
#pragma unroll
    for (int mi = 0; mi < 4; ++mi) {
      int r = wm + mi * 16 + l16;
      fAH[mi] = *(const u16x8*)&AsH[r * LDK + qd * 8];
      fAL[mi] = *(const u16x8*)&AsL[r * LDK + qd * 8];
    }
#pragma unroll
    for (int ei = 0; ei < 4; ++ei) {
      int r = we + ei * 16 + l16;
      fBH[ei] = *(const u16x8*)&BsH[r * LDK + qd * 8];
      fBL[ei] = *(const u16x8*)&BsL[r * LDK + qd * 8];
    }
#pragma unroll
    for (int mi = 0; mi < 4; ++mi)
#pragma unroll
      for (int ei = 0; ei < 4; ++ei) {
        acc[mi][ei] = mfma_bf16(fAH[mi], fBH[ei], acc[mi][ei]);
        acc[mi][ei] = mfma_bf16(fAH[mi], fBL[ei], acc[mi][ei]);
        acc[mi][ei] = mfma_bf16(fAL[mi], fBH[ei], acc[mi][ei]);
      }
    __syncthreads();
  }

  /* C/D layout: row = qd*4 + reg, col = lane&15 (verified mapping) */
#pragma unroll
  for (int mi = 0; mi < 4; ++mi)
#pragma unroll
    for (int ei = 0; ei < 4; ++ei)
#pragma unroll
      for (int r = 0; r < 4; ++r) {
        int row = m0 + wm + mi * 16 + qd * 4 + r;
        int col = e0 + we + ei * 16 + l16;
        QKV[(size_t)row * E3 + col] = acc[mi][ei][r];
      }
}

/* ---------------- Sliding-window attention ----------------
 * One block per (b, n). Padded positions (r<0) have logit 0.0 (zero k rows)
 * and v = 0 -- they DO participate in the softmax denominator. */
__global__ __launch_bounds__(256) void attn_kernel(const float* __restrict__ QKV,
                                                   float* __restrict__ Out) {
  const int mIdx = blockIdx.x;      /* 0..4095 */
  const int b = mIdx >> 11;
  const int n = mIdx & 2047;
  const int tid = threadIdx.x;

  __shared__ __align__(16) float q_s[D_];
  __shared__ float att[W_];
  __shared__ __align__(16) float4 opart[128];

  const float* qrow = QKV + (size_t)mIdx * E3;
  q_s[tid] = qrow[tid];
  q_s[tid + 256] = qrow[tid + 256];
  __syncthreads();

  /* logits: group g = tid>>3 (32 groups), 8 lanes split D; each group does
   * w = g + 32*wi. Per (w): lane reads float4 at d4 = sub + 8j -> 8 lanes
   * cover 128 B contiguous. */
  const int g = tid >> 3;
  const int sub = tid & 7;
  const float* kbase = QKV + (size_t)(b * N_) * E3 + D_;
  const float4* q4 = (const float4*)q_s;
#pragma unroll
  for (int wi = 0; wi < 4; ++wi) {
    const int w = g + 32 * wi;
    const int r = n - (W_ - 1) + w;
    float p = 0.f;
    if (r >= 0) {
      const float4* kr = (const float4*)(kbase + (size_t)r * E3);
#pragma unroll
      for (int j = 0; j < 16; ++j) {
        float4 kv = kr[sub + 8 * j];
        float4 qv = q4[sub + 8 * j];
        p += kv.x * qv.x + kv.y * qv.y + kv.z * qv.z + kv.w * qv.w;
      }
    }
    p += __shfl_xor(p, 1);
    p += __shfl_xor(p, 2);
    p += __shfl_xor(p, 4);
    if (sub == 0) att[w] = p; /* p == 0 when r < 0: matches zero-pad logits */
  }
  __syncthreads();

  /* softmax over 128 logits: wave 0, 2 values per lane */
  if (tid < 64) {
    float l0 = att[tid], l1 = att[tid + 64];
    float mx = fmaxf(l0, l1);
#pragma unroll
    for (int o = 1; o < 64; o <<= 1) mx = fmaxf(mx, __shfl_xor(mx, o));
    float e0 = __expf(l0 - mx), e1 = __expf(l1 - mx);
    float s = e0 + e1;
#pragma unroll
    for (int o = 1; o < 64; o <<= 1) s += __shfl_xor(s, o);
    float inv = 1.f / s;
    att[tid] = e0 * inv;
    att[tid + 64] = e1 * inv;
  }
  __syncthreads();

  /* out[d] = sum_w att[w] * v[r(w)][d]; threads: d4 = tid&127 (float4 col),
   * wh = tid>>7 splits the w-range in half; combine via LDS. */
  const int d4 = tid & 127;
  const int wh = tid >> 7;
  f32x4 acc = (f32x4){0.f, 0.f, 0.f, 0.f};
  const float* vbase = QKV + (size_t)(b * N_) * E3 + 2 * D_;
  for (int w = wh * 64; w < wh * 64 + 64; ++w) {
    int r = n - (W_ - 1) + w;
    if (r >= 0) {
      float a = att[w];
      float4 vv = ((const float4*)(vbase + (size_t)r * E3))[d4];
      acc.x += a * vv.x;
      acc.y += a * vv.y;
      acc.z += a * vv.z;
      acc.w += a * vv.w;
    }
  }
  if (wh) opart[d4] = (float4){acc.x, acc.y, acc.z, acc.w};
  __syncthreads();
  if (!wh) {
    float4 o2 = opart[d4];
    float4 res = {acc.x + o2.x, acc.y + o2.y, acc.z + o2.z, acc.w + o2.w};
    ((float4*)(Out + (size_t)mIdx * D_))[d4] = res;
  }
}

extern "C" void kernel_launch(void* const* d_in, const int* in_sizes, int n_in,
                              void* d_out, int out_size, void* d_ws, size_t ws_size,
                              hipStream_t stream) {
  const float* x = (const float*)d_in[0];    /* (B, N, F) fp32 */
  const float* wl = (const float*)d_in[1];   /* (3D, F) fp32 */
  float* out = (float*)d_out;                /* (B, N, D) fp32 */
  float* qkv = (float*)d_ws;                 /* (B*N, 3D) fp32 = 25.2 MB scratch */

  dim3 g1(MTOT / TM, E3 / TE); /* 32 x 12 */
  qkv_gemm<<<g1, 256, 0, stream>>>(x, wl, qkv);
  attn_kernel<<<MTOT, 256, 0, stream>>>(qkv, out);
}